// Round 1
// baseline (686.450 us; speedup 1.0000x reference)
//
#include <hip/hip_runtime.h>

#define Lnum 12
#define Bnum 2
#define Snum 2048
#define Dnum 768
#define QKnum 128
#define SCALE 0.08838834764831845f

typedef __attribute__((ext_vector_type(8))) __bf16 bf16x8;
typedef __attribute__((ext_vector_type(4))) float f32x4;

__device__ inline unsigned short f2bf(float f) {
    unsigned int u = __float_as_uint(f);
    unsigned int r = u + 0x7FFFu + ((u >> 16) & 1u);
    return (unsigned short)(r >> 16);
}

// ---------------- weight fp32 -> bf16 conversion ----------------
__global__ void f2bf_kernel(const float* __restrict__ in, unsigned short* __restrict__ out, int n) {
    for (int i = blockIdx.x * 256 + threadIdx.x; i < n; i += gridDim.x * 256)
        out[i] = f2bf(in[i]);
}

// ---------------- fused front: mean, q, k, scores, softmax, hbar ----------------
__global__ __launch_bounds__(256) void fused_front(
    const float* __restrict__ x,    // [12][2][2048][768]
    const float* __restrict__ Wq,   // [768][128]
    const float* __restrict__ bq,   // [128]
    const float* __restrict__ Wk,   // [768][128]
    const float* __restrict__ bk,   // [128]
    unsigned short* __restrict__ hbar)  // [4096][768], row = b*2048+s, bf16
{
    __shared__ float xs[Lnum * Dnum];   // 36 KB
    __shared__ float qin[Dnum];
    __shared__ float qv[QKnum];
    __shared__ float red[256];
    __shared__ float sc[Lnum];
    __shared__ float scp[2];
    __shared__ float attn[Lnum];

    const int tid = threadIdx.x;
    const int bid = blockIdx.x;
    const int s = bid >> 1, b = bid & 1;

    // stage the (s,b) slice of all 12 layers
    for (int i = tid; i < Lnum * Dnum; i += 256) {
        int l = i / Dnum, d = i - l * Dnum;
        xs[i] = x[(((size_t)(l * Bnum + b) * Snum + s) * Dnum) + d];
    }
    __syncthreads();

    // q_in = mean over layers
    for (int d = tid; d < Dnum; d += 256) {
        float sum = 0.f;
        #pragma unroll
        for (int l = 0; l < Lnum; ++l) sum += xs[l * Dnum + d];
        qin[d] = sum * (1.0f / 12.0f);
    }
    __syncthreads();

    // q = relu(q_in @ Wq + bq), 2 half-K partials per output
    {
        int j = tid & 127, half = tid >> 7;
        float acc = 0.f;
        int d0 = half * 384;
        for (int d = d0; d < d0 + 384; ++d)
            acc += qin[d] * Wq[d * QKnum + j];
        red[tid] = acc;
        __syncthreads();
        if (tid < 128) {
            float v = red[tid] + red[tid + 128] + bq[tid];
            qv[tid] = v > 0.f ? v : 0.f;
        }
        __syncthreads();
    }

    // k_l = relu(x_l @ Wk + bk); score_l = q . k_l  (Wk read once per block)
    {
        int j = tid & 127, half = tid >> 7;
        float acc[Lnum];
        #pragma unroll
        for (int l = 0; l < Lnum; ++l) acc[l] = 0.f;
        int d0 = half * 384;
        for (int d = d0; d < d0 + 384; ++d) {
            float w = Wk[d * QKnum + j];
            #pragma unroll
            for (int l = 0; l < Lnum; ++l) acc[l] += xs[l * Dnum + d] * w;
        }
        for (int l = 0; l < Lnum; ++l) {
            red[tid] = acc[l];
            __syncthreads();
            if (tid < 128) {
                float kj = red[tid] + red[tid + 128] + bk[tid];
                kj = kj > 0.f ? kj : 0.f;
                float prod = kj * qv[tid];
                #pragma unroll
                for (int off = 32; off > 0; off >>= 1)
                    prod += __shfl_down(prod, off, 64);
                if ((tid & 63) == 0) scp[tid >> 6] = prod;
            }
            __syncthreads();
            if (tid == 0) sc[l] = (scp[0] + scp[1]) * SCALE;
            __syncthreads();
        }
    }

    // softmax over the 12 layer scores
    if (tid == 0) {
        float m = sc[0];
        #pragma unroll
        for (int l = 1; l < Lnum; ++l) m = fmaxf(m, sc[l]);
        float den = 0.f, e[Lnum];
        #pragma unroll
        for (int l = 0; l < Lnum; ++l) { e[l] = expf(sc[l] - m); den += e[l]; }
        float inv = 1.0f / den;
        #pragma unroll
        for (int l = 0; l < Lnum; ++l) attn[l] = e[l] * inv;
    }
    __syncthreads();

    // hbar = sum_l attn_l * x_l  -> bf16, row = b*S+s (pre-transposed for (B,S,*))
    const size_t r = (size_t)b * Snum + s;
    for (int d = tid; d < Dnum; d += 256) {
        float h = 0.f;
        #pragma unroll
        for (int l = 0; l < Lnum; ++l) h += attn[l] * xs[l * Dnum + d];
        hbar[r * Dnum + d] = f2bf(h);
    }
}

// ---------------- generic bf16 MFMA GEMM: out = act(A @ B + bias) ----------------
// A: [M][K] bf16 row-major, B: [K][N] bf16 row-major. Block tile 64x64, 4 waves of 32x32.
template <int RELU, int OUT_BF16>
__global__ __launch_bounds__(256) void gemm_bf16(
    const unsigned short* __restrict__ A,
    const unsigned short* __restrict__ Bm,
    const float* __restrict__ bias,
    void* __restrict__ out,
    int M, int N, int K)
{
    __shared__ __align__(16) unsigned short As[64][40];
    __shared__ __align__(16) unsigned short Bs[64][40];  // Bs[col][k]

    const int tid = threadIdx.x;
    const int bn = blockIdx.x;   // N / 64
    const int bm = blockIdx.y;   // M / 64
    const int wid = tid >> 6, lane = tid & 63;
    const int wm = (wid >> 1) * 32, wn = (wid & 1) * 32;
    const int lr = lane & 15, g = lane >> 4;
    const int r0 = bm * 64, c0 = bn * 64;

    f32x4 acc[2][2] = {};

    for (int k0 = 0; k0 < K; k0 += 32) {
        __syncthreads();
        // stage A tile: 64 rows x 32 k
        {
            int row = tid >> 2, kc = (tid & 3) * 8;
            *(uint4*)&As[row][kc] =
                *(const uint4*)(A + (size_t)(r0 + row) * K + k0 + kc);
        }
        // stage B tile transposed: 32 k x 64 cols -> Bs[col][k]
        {
            int kk = tid >> 3, cc = (tid & 7) * 8;
            unsigned short v[8];
            *(uint4*)v = *(const uint4*)(Bm + (size_t)(k0 + kk) * N + c0 + cc);
            #pragma unroll
            for (int j = 0; j < 8; ++j) Bs[cc + j][kk] = v[j];
        }
        __syncthreads();

        bf16x8 aF[2], bF[2];
        #pragma unroll
        for (int m = 0; m < 2; ++m)
            aF[m] = *(const bf16x8*)&As[wm + m * 16 + lr][g * 8];
        #pragma unroll
        for (int n = 0; n < 2; ++n)
            bF[n] = *(const bf16x8*)&Bs[wn + n * 16 + lr][g * 8];
        #pragma unroll
        for (int m = 0; m < 2; ++m)
            #pragma unroll
            for (int n = 0; n < 2; ++n)
                acc[m][n] = __builtin_amdgcn_mfma_f32_16x16x32_bf16(
                    aF[m], bF[n], acc[m][n], 0, 0, 0);
    }

    // epilogue: C/D mapping col = lane&15, row = (lane>>4)*4 + reg (guide-verified)
    #pragma unroll
    for (int m = 0; m < 2; ++m)
        #pragma unroll
        for (int n = 0; n < 2; ++n) {
            int col = c0 + wn + n * 16 + lr;
            float bcol = bias[col];
            #pragma unroll
            for (int reg = 0; reg < 4; ++reg) {
                int row = r0 + wm + m * 16 + g * 4 + reg;
                float v = acc[m][n][reg] + bcol;
                if (RELU) v = v > 0.f ? v : 0.f;
                if (OUT_BF16)
                    ((unsigned short*)out)[(size_t)row * N + col] = f2bf(v);
                else
                    ((float*)out)[(size_t)row * N + col] = v;
            }
        }
}

extern "C" void kernel_launch(void* const* d_in, const int* in_sizes, int n_in,
                              void* d_out, int out_size, void* d_ws, size_t ws_size,
                              hipStream_t stream) {
    (void)in_sizes; (void)n_in; (void)out_size; (void)ws_size;

    const float* x  = (const float*)d_in[0];
    const float* Wq = (const float*)d_in[1];
    const float* bq = (const float*)d_in[2];
    const float* Wk = (const float*)d_in[3];
    const float* bk = (const float*)d_in[4];
    const float* Wv = (const float*)d_in[5];
    const float* bv = (const float*)d_in[6];
    const float* W1 = (const float*)d_in[7];
    const float* b1 = (const float*)d_in[8];
    const float* W2 = (const float*)d_in[9];
    const float* b2 = (const float*)d_in[10];

    char* p = (char*)d_ws;
    unsigned short* hbar = (unsigned short*)p; p += (size_t)4096 * 768 * 2;
    unsigned short* aggb = (unsigned short*)p; p += (size_t)4096 * 512 * 2;
    unsigned short* midb = (unsigned short*)p; p += (size_t)4096 * 256 * 2;
    unsigned short* Wvb  = (unsigned short*)p; p += (size_t)768 * 512 * 2;
    unsigned short* W1b  = (unsigned short*)p; p += (size_t)512 * 256 * 2;
    unsigned short* W2b  = (unsigned short*)p; p += (size_t)256 * 32000 * 2;

    // weight conversions (fp32 -> bf16)
    f2bf_kernel<<<dim3(1536), dim3(256), 0, stream>>>(Wv, Wvb, 768 * 512);
    f2bf_kernel<<<dim3(512),  dim3(256), 0, stream>>>(W1, W1b, 512 * 256);
    f2bf_kernel<<<dim3(4096), dim3(256), 0, stream>>>(W2, W2b, 256 * 32000);

    // fused front -> hbar (bf16, rows = b*S+s)
    fused_front<<<dim3(4096), dim3(256), 0, stream>>>(x, Wq, bq, Wk, bk, hbar);

    // agg = hbar @ Wv + bv          (4096 x 512, K=768) -> bf16
    gemm_bf16<0, 1><<<dim3(512 / 64, 64), dim3(256), 0, stream>>>(
        hbar, Wvb, bv, aggb, 4096, 512, 768);
    // mid = relu(agg @ W1 + b1)     (4096 x 256, K=512) -> bf16
    gemm_bf16<1, 1><<<dim3(256 / 64, 64), dim3(256), 0, stream>>>(
        aggb, W1b, b1, midb, 4096, 256, 512);
    // out = mid @ W2 + b2           (4096 x 32000, K=256) -> fp32
    gemm_bf16<0, 0><<<dim3(32000 / 64, 64), dim3(256), 0, stream>>>(
        midb, W2b, b2, d_out, 4096, 32000, 256);
}

// Round 2
// 348.995 us; speedup vs baseline: 1.9669x; 1.9669x over previous
//
#include <hip/hip_runtime.h>

#define Snum 2048
#define SCALE 0.08838834764831845f

typedef __attribute__((ext_vector_type(8))) __bf16 bf16x8;
typedef __attribute__((ext_vector_type(4))) float f32x4;

__device__ inline unsigned short f2bf(float f) {
    unsigned int u = __float_as_uint(f);
    unsigned int r = u + 0x7FFFu + ((u >> 16) & 1u);
    return (unsigned short)(r >> 16);
}
__device__ inline float bf2f(unsigned short u) {
    return __uint_as_float(((unsigned)u) << 16);
}
__device__ inline void gld_lds16(const unsigned short* g, unsigned short* l) {
    __builtin_amdgcn_global_load_lds(
        (const __attribute__((address_space(1))) unsigned int*)g,
        (__attribute__((address_space(3))) unsigned int*)l, 16, 0, 0);
}

// ---------------- tiled transpose + fp32->bf16: in [K][N] -> out [N][K] ----------------
__global__ __launch_bounds__(256) void transpose_f2bf(
    const float* __restrict__ in, unsigned short* __restrict__ out, int K, int N)
{
    __shared__ float t[32][33];
    const int bx = blockIdx.x;           // N / 32
    const int by = blockIdx.y;           // K / 32
    const int tx = threadIdx.x & 31, ty = threadIdx.x >> 5;
    #pragma unroll
    for (int i = 0; i < 4; ++i) {
        int k = by * 32 + ty + i * 8, n = bx * 32 + tx;
        t[ty + i * 8][tx] = in[(size_t)k * N + n];
    }
    __syncthreads();
    #pragma unroll
    for (int i = 0; i < 4; ++i) {
        int n = bx * 32 + ty + i * 8, k = by * 32 + tx;
        out[(size_t)n * K + k] = f2bf(t[tx][ty + i * 8]);
    }
}

// ---------------- mean over layers: x [12][2][2048][768] -> hmean bf16 [4096][768] ----------------
__global__ __launch_bounds__(256) void mean_kernel(
    const float* __restrict__ x, unsigned short* __restrict__ hmean)
{
    int idx = blockIdx.x * 256 + threadIdx.x;     // over 4096*192 float4 slots
    if (idx >= 4096 * 192) return;
    int r = idx / 192, jv = idx % 192;
    int b = r >> 11, s = r & 2047;
    float a0 = 0.f, a1 = 0.f, a2 = 0.f, a3 = 0.f;
    #pragma unroll
    for (int l = 0; l < 12; ++l) {
        const float4 v = *(const float4*)(x + ((size_t)(l * 2 + b) * Snum + s) * 768 + jv * 4);
        a0 += v.x; a1 += v.y; a2 += v.z; a3 += v.w;
    }
    const float inv = 1.0f / 12.0f;
    ushort4 o;
    o.x = f2bf(a0 * inv); o.y = f2bf(a1 * inv); o.z = f2bf(a2 * inv); o.w = f2bf(a3 * inv);
    *(ushort4*)(hmean + (size_t)r * 768 + jv * 4) = o;
}

// ---------------- scores + softmax + weighted hidden sum ----------------
__global__ __launch_bounds__(256) void scores_hbar(
    const float* __restrict__ x,             // [12][2][2048][768] fp32
    const unsigned short* __restrict__ Q,    // [4096][128] bf16, row = b*S+s
    const unsigned short* __restrict__ Kall, // [49152][128] bf16, row = (l*2+b)*S+s
    unsigned short* __restrict__ hbar)       // [4096][768] bf16
{
    const int wid = threadIdx.x >> 6, lane = threadIdx.x & 63;
    const int r = blockIdx.x * 4 + wid;      // 1024 blocks * 4 waves
    const int b = r >> 11, s = r & 2047;

    const unsigned short* qrow = Q + (size_t)r * 128 + lane * 2;
    const float q0 = bf2f(qrow[0]), q1 = bf2f(qrow[1]);

    float sc[12];
    #pragma unroll
    for (int l = 0; l < 12; ++l) {
        const unsigned short* krow = Kall + ((size_t)(l * 2 + b) * Snum + s) * 128 + lane * 2;
        float p = q0 * bf2f(krow[0]) + q1 * bf2f(krow[1]);
        #pragma unroll
        for (int off = 32; off > 0; off >>= 1) p += __shfl_xor(p, off, 64);
        sc[l] = p * SCALE;
    }
    // softmax over 12 (redundant on every lane)
    float m = sc[0];
    #pragma unroll
    for (int l = 1; l < 12; ++l) m = fmaxf(m, sc[l]);
    float att[12], den = 0.f;
    #pragma unroll
    for (int l = 0; l < 12; ++l) { att[l] = __expf(sc[l] - m); den += att[l]; }
    const float inv = 1.0f / den;
    #pragma unroll
    for (int l = 0; l < 12; ++l) att[l] *= inv;

    // hbar = sum_l att[l] * x_l   (fp32 source, fp32 accumulate)
    #pragma unroll
    for (int jv = 0; jv < 3; ++jv) {
        const int d0 = jv * 256 + lane * 4;
        float a0 = 0.f, a1 = 0.f, a2 = 0.f, a3 = 0.f;
        #pragma unroll
        for (int l = 0; l < 12; ++l) {
            const float4 v = *(const float4*)(x + ((size_t)(l * 2 + b) * Snum + s) * 768 + d0);
            a0 += att[l] * v.x; a1 += att[l] * v.y; a2 += att[l] * v.z; a3 += att[l] * v.w;
        }
        ushort4 o;
        o.x = f2bf(a0); o.y = f2bf(a1); o.z = f2bf(a2); o.w = f2bf(a3);
        *(ushort4*)(hbar + (size_t)r * 768 + d0) = o;
    }
}

// ---------------- 64x64 bf16 MFMA GEMM (small shapes): out = act(A @ Bt^T + bias) ----------------
// A: [M][K] bf16 row-major; Bt: [N][K] bf16 row-major (pre-transposed weights)
template <int RELU, int OUT_BF16>
__global__ __launch_bounds__(256) void gemm64(
    const unsigned short* __restrict__ A, const unsigned short* __restrict__ Bt,
    const float* __restrict__ bias, void* __restrict__ out, int M, int N, int K)
{
    __shared__ __align__(16) unsigned short As[64][40];
    __shared__ __align__(16) unsigned short Bs[64][40];
    const int tid = threadIdx.x;
    const int bn = blockIdx.x, bm = blockIdx.y;
    const int wid = tid >> 6, lane = tid & 63;
    const int wm = (wid >> 1) * 32, wn = (wid & 1) * 32;
    const int lr = lane & 15, g = lane >> 4;
    const int r0 = bm * 64, c0 = bn * 64;

    f32x4 acc[2][2] = {};
    const int row = tid >> 2, kc = (tid & 3) * 8;

    for (int k0 = 0; k0 < K; k0 += 32) {
        __syncthreads();
        *(uint4*)&As[row][kc] = *(const uint4*)(A  + (size_t)(r0 + row) * K + k0 + kc);
        *(uint4*)&Bs[row][kc] = *(const uint4*)(Bt + (size_t)(c0 + row) * K + k0 + kc);
        __syncthreads();

        bf16x8 aF[2], bF[2];
        #pragma unroll
        for (int mm = 0; mm < 2; ++mm) aF[mm] = *(const bf16x8*)&As[wm + mm * 16 + lr][g * 8];
        #pragma unroll
        for (int nn = 0; nn < 2; ++nn) bF[nn] = *(const bf16x8*)&Bs[wn + nn * 16 + lr][g * 8];
        #pragma unroll
        for (int mm = 0; mm < 2; ++mm)
            #pragma unroll
            for (int nn = 0; nn < 2; ++nn)
                acc[mm][nn] = __builtin_amdgcn_mfma_f32_16x16x32_bf16(aF[mm], bF[nn], acc[mm][nn], 0, 0, 0);
    }

    #pragma unroll
    for (int mm = 0; mm < 2; ++mm)
        #pragma unroll
        for (int nn = 0; nn < 2; ++nn) {
            int col = c0 + wn + nn * 16 + lr;
            float bcol = bias[col];
            #pragma unroll
            for (int reg = 0; reg < 4; ++reg) {
                int orow = r0 + wm + mm * 16 + g * 4 + reg;
                float v = acc[mm][nn][reg] + bcol;
                if (RELU) v = v > 0.f ? v : 0.f;
                if (OUT_BF16) ((unsigned short*)out)[(size_t)orow * N + col] = f2bf(v);
                else          ((float*)out)[(size_t)orow * N + col] = v;
            }
        }
}

// ---------------- 128x128 bf16 MFMA GEMM, global_load_lds staging (m97 structure) ----------------
// A: [M][K] (bf16, or fp32 reg-staged if AF32); Bt: [N][K] bf16
template <int AF32, int RELU, int OUT_BF16>
__global__ __launch_bounds__(256) void gemm128(
    const void* __restrict__ Ap, const unsigned short* __restrict__ Bt,
    const float* __restrict__ bias, void* __restrict__ out, int M, int N, int K)
{
    __shared__ __align__(16) unsigned short As[128 * 32];
    __shared__ __align__(16) unsigned short Bs[128 * 32];
    const int tid = threadIdx.x;
    const int bn = blockIdx.x, bm = blockIdx.y;
    const int wid = tid >> 6, lane = tid & 63;
    const int wm = (wid >> 1) * 64, wn = (wid & 1) * 64;
    const int lr = lane & 15, g = lane >> 4;
    const int r0 = bm * 128, c0 = bn * 128;

    f32x4 acc[4][4] = {};

    for (int k0 = 0; k0 < K; k0 += 32) {
        __syncthreads();
        if (AF32) {
            // reg-stage A fp32 -> bf16 (16 elems/thread)
            const float* Af = (const float*)Ap;
            const int arow = tid >> 1, akc = (tid & 1) * 16;
            const float* src = Af + (size_t)(r0 + arow) * K + k0 + akc;
            unsigned short v[16];
            #pragma unroll
            for (int j = 0; j < 16; ++j) v[j] = f2bf(src[j]);
            *(uint4*)&As[arow * 32 + akc]     = *(uint4*)&v[0];
            *(uint4*)&As[arow * 32 + akc + 8] = *(uint4*)&v[8];
        } else {
            const unsigned short* Ab = (const unsigned short*)Ap;
            #pragma unroll
            for (int c = 0; c < 2; ++c) {
                int rr = wid * 32 + c * 16;
                gld_lds16(Ab + (size_t)(r0 + rr + (lane >> 2)) * K + k0 + (lane & 3) * 8,
                          &As[rr * 32]);
            }
        }
        #pragma unroll
        for (int c = 0; c < 2; ++c) {
            int rr = wid * 32 + c * 16;
            gld_lds16(Bt + (size_t)(c0 + rr + (lane >> 2)) * K + k0 + (lane & 3) * 8,
                      &Bs[rr * 32]);
        }
        __syncthreads();

        bf16x8 aF[4], bF[4];
        #pragma unroll
        for (int mm = 0; mm < 4; ++mm) aF[mm] = *(const bf16x8*)&As[(wm + mm * 16 + lr) * 32 + g * 8];
        #pragma unroll
        for (int nn = 0; nn < 4; ++nn) bF[nn] = *(const bf16x8*)&Bs[(wn + nn * 16 + lr) * 32 + g * 8];
        #pragma unroll
        for (int mm = 0; mm < 4; ++mm)
            #pragma unroll
            for (int nn = 0; nn < 4; ++nn)
                acc[mm][nn] = __builtin_amdgcn_mfma_f32_16x16x32_bf16(aF[mm], bF[nn], acc[mm][nn], 0, 0, 0);
    }

    #pragma unroll
    for (int mm = 0; mm < 4; ++mm)
        #pragma unroll
        for (int nn = 0; nn < 4; ++nn) {
            int col = c0 + wn + nn * 16 + lr;
            float bcol = bias[col];
            #pragma unroll
            for (int reg = 0; reg < 4; ++reg) {
                int orow = r0 + wm + mm * 16 + g * 4 + reg;
                float v = acc[mm][nn][reg] + bcol;
                if (RELU) v = v > 0.f ? v : 0.f;
                if (OUT_BF16) ((unsigned short*)out)[(size_t)orow * N + col] = f2bf(v);
                else          ((float*)out)[(size_t)orow * N + col] = v;
            }
        }
}

extern "C" void kernel_launch(void* const* d_in, const int* in_sizes, int n_in,
                              void* d_out, int out_size, void* d_ws, size_t ws_size,
                              hipStream_t stream) {
    (void)in_sizes; (void)n_in; (void)out_size; (void)ws_size;

    const float* x  = (const float*)d_in[0];
    const float* Wq = (const float*)d_in[1];
    const float* bq = (const float*)d_in[2];
    const float* Wk = (const float*)d_in[3];
    const float* bk = (const float*)d_in[4];
    const float* Wv = (const float*)d_in[5];
    const float* bv = (const float*)d_in[6];
    const float* W1 = (const float*)d_in[7];
    const float* b1 = (const float*)d_in[8];
    const float* W2 = (const float*)d_in[9];
    const float* b2 = (const float*)d_in[10];

    char* p = (char*)d_ws;
    unsigned short* Wqt   = (unsigned short*)p; p += (size_t)128 * 768 * 2;
    unsigned short* Wkt   = (unsigned short*)p; p += (size_t)128 * 768 * 2;
    unsigned short* Wvt   = (unsigned short*)p; p += (size_t)512 * 768 * 2;
    unsigned short* W1t   = (unsigned short*)p; p += (size_t)256 * 512 * 2;
    unsigned short* W2t   = (unsigned short*)p; p += (size_t)32000 * 256 * 2;
    unsigned short* hmean = (unsigned short*)p; p += (size_t)4096 * 768 * 2;
    unsigned short* Qb    = (unsigned short*)p; p += (size_t)4096 * 128 * 2;
    unsigned short* Kall  = (unsigned short*)p; p += (size_t)49152 * 128 * 2;
    unsigned short* hbar  = (unsigned short*)p; p += (size_t)4096 * 768 * 2;
    unsigned short* aggb  = (unsigned short*)p; p += (size_t)4096 * 512 * 2;
    unsigned short* midb  = (unsigned short*)p; p += (size_t)4096 * 256 * 2;

    // weight transpose+convert: [K][N] fp32 -> [N][K] bf16
    transpose_f2bf<<<dim3(128 / 32, 768 / 32), dim3(256), 0, stream>>>(Wq, Wqt, 768, 128);
    transpose_f2bf<<<dim3(128 / 32, 768 / 32), dim3(256), 0, stream>>>(Wk, Wkt, 768, 128);
    transpose_f2bf<<<dim3(512 / 32, 768 / 32), dim3(256), 0, stream>>>(Wv, Wvt, 768, 512);
    transpose_f2bf<<<dim3(256 / 32, 512 / 32), dim3(256), 0, stream>>>(W1, W1t, 512, 256);
    transpose_f2bf<<<dim3(32000 / 32, 256 / 32), dim3(256), 0, stream>>>(W2, W2t, 256, 32000);

    // hmean = mean over layers (bf16, row = b*S+s)
    mean_kernel<<<dim3(3072), dim3(256), 0, stream>>>(x, hmean);

    // Q = relu(hmean @ Wq + bq)   [4096][128]
    gemm64<1, 1><<<dim3(128 / 64, 4096 / 64), dim3(256), 0, stream>>>(
        hmean, Wqt, bq, Qb, 4096, 128, 768);

    // Kall = relu(x @ Wk + bk)    [49152][128]  (A = fp32 x, reg-staged)
    gemm128<1, 1, 1><<<dim3(128 / 128, 49152 / 128), dim3(256), 0, stream>>>(
        x, Wkt, bk, Kall, 49152, 128, 768);

    // scores -> softmax over layers -> hbar  [4096][768]
    scores_hbar<<<dim3(1024), dim3(256), 0, stream>>>(x, Qb, Kall, hbar);

    // agg = hbar @ Wv + bv        [4096][512]
    gemm128<0, 0, 1><<<dim3(512 / 128, 4096 / 128), dim3(256), 0, stream>>>(
        hbar, Wvt, bv, aggb, 4096, 512, 768);

    // mid = relu(agg @ W1 + b1)   [4096][256]
    gemm64<1, 1><<<dim3(256 / 64, 4096 / 64), dim3(256), 0, stream>>>(
        aggb, W1t, b1, midb, 4096, 256, 512);

    // out = mid @ W2 + b2         [4096][32000] fp32
    gemm128<0, 0, 0><<<dim3(32000 / 128, 4096 / 128), dim3(256), 0, stream>>>(
        midb, W2t, b2, d_out, 4096, 32000, 256);
}

// Round 3
// 340.796 us; speedup vs baseline: 2.0143x; 1.0241x over previous
//
#include <hip/hip_runtime.h>

#define Snum 2048
#define SCALE 0.08838834764831845f

typedef __attribute__((ext_vector_type(8))) __bf16 bf16x8;
typedef __attribute__((ext_vector_type(4))) float f32x4;

__device__ inline unsigned short f2bf(float f) {
    unsigned int u = __float_as_uint(f);
    unsigned int r = u + 0x7FFFu + ((u >> 16) & 1u);
    return (unsigned short)(r >> 16);
}
__device__ inline float bf2f(unsigned short u) {
    return __uint_as_float(((unsigned)u) << 16);
}
__device__ inline void gld_lds16(const unsigned short* g, unsigned short* l) {
    __builtin_amdgcn_global_load_lds(
        (const __attribute__((address_space(1))) unsigned int*)g,
        (__attribute__((address_space(3))) unsigned int*)l, 16, 0, 0);
}

// ---------------- tiled transpose + fp32->bf16: in [K][N] -> out [N][K] ----------------
__global__ __launch_bounds__(256) void transpose_f2bf(
    const float* __restrict__ in, unsigned short* __restrict__ out, int K, int N)
{
    __shared__ float t[32][33];
    const int bx = blockIdx.x;           // N / 32
    const int by = blockIdx.y;           // K / 32
    const int tx = threadIdx.x & 31, ty = threadIdx.x >> 5;
    #pragma unroll
    for (int i = 0; i < 4; ++i) {
        int k = by * 32 + ty + i * 8, n = bx * 32 + tx;
        t[ty + i * 8][tx] = in[(size_t)k * N + n];
    }
    __syncthreads();
    #pragma unroll
    for (int i = 0; i < 4; ++i) {
        int n = bx * 32 + ty + i * 8, k = by * 32 + tx;
        out[(size_t)n * K + k] = f2bf(t[tx][ty + i * 8]);
    }
}

// ---------------- proj_qk: one pass over x computes Kall = relu(x@Wk+bk) and Pq = x@Wq ----------------
// A: x fp32 [49152][768] (row = (l*2+b)*2048+s), Bt: Wqkt bf16 [256][768] (rows 0-127 Wk^T, 128-255 Wq^T)
__global__ __launch_bounds__(512) void proj_qk(
    const float* __restrict__ x, const unsigned short* __restrict__ Bt,
    const float* __restrict__ bk,
    unsigned short* __restrict__ Kall,   // [49152][128] bf16
    unsigned short* __restrict__ Pq)     // [49152][128] bf16
{
    __shared__ __align__(16) unsigned short As[128 * 32];   // 8 KB
    __shared__ __align__(16) unsigned short Bs[256 * 32];   // 16 KB
    const int tid = threadIdx.x;
    const int wid = tid >> 6, lane = tid & 63;
    const int wm = (wid >> 2) * 64, wn = (wid & 3) * 64;
    const int lr = lane & 15, g = lane >> 4;
    const int r0 = blockIdx.x * 128;
    const int K = 768;

    f32x4 acc[4][4] = {};
    const int arow = tid >> 2, akc = (tid & 2) * 4;  // t>>2 in [0,128); (t&3)*8? need 8 floats/thread
    // 512 threads * 8 floats = 4096 = 128x32. row = tid>>2, kc = (tid&3)*8
    const int arow2 = tid >> 2, akc2 = (tid & 3) * 8;
    (void)arow; (void)akc;

    for (int k0 = 0; k0 < K; k0 += 32) {
        __syncthreads();
        // stage A: fp32 -> bf16, 8 elems/thread
        {
            const float* src = x + (size_t)(r0 + arow2) * K + k0 + akc2;
            float4 v0 = *(const float4*)src;
            float4 v1 = *(const float4*)(src + 4);
            unsigned short v[8];
            v[0] = f2bf(v0.x); v[1] = f2bf(v0.y); v[2] = f2bf(v0.z); v[3] = f2bf(v0.w);
            v[4] = f2bf(v1.x); v[5] = f2bf(v1.y); v[6] = f2bf(v1.z); v[7] = f2bf(v1.w);
            *(uint4*)&As[arow2 * 32 + akc2] = *(uint4*)v;
        }
        // stage B: 256 rows x 32 k via global_load_lds, 2 rounds of 16 rows per wave
        #pragma unroll
        for (int c = 0; c < 2; ++c) {
            int rr = wid * 32 + c * 16;
            gld_lds16(Bt + (size_t)(rr + (lane >> 2)) * K + k0 + (lane & 3) * 8,
                      &Bs[rr * 32]);
        }
        __syncthreads();

        bf16x8 aF[4], bF[4];
        #pragma unroll
        for (int mm = 0; mm < 4; ++mm) aF[mm] = *(const bf16x8*)&As[(wm + mm * 16 + lr) * 32 + g * 8];
        #pragma unroll
        for (int nn = 0; nn < 4; ++nn) bF[nn] = *(const bf16x8*)&Bs[(wn + nn * 16 + lr) * 32 + g * 8];
        #pragma unroll
        for (int mm = 0; mm < 4; ++mm)
            #pragma unroll
            for (int nn = 0; nn < 4; ++nn)
                acc[mm][nn] = __builtin_amdgcn_mfma_f32_16x16x32_bf16(aF[mm], bF[nn], acc[mm][nn], 0, 0, 0);
    }

    #pragma unroll
    for (int mm = 0; mm < 4; ++mm)
        #pragma unroll
        for (int nn = 0; nn < 4; ++nn) {
            int col = wn + nn * 16 + lr;
            #pragma unroll
            for (int reg = 0; reg < 4; ++reg) {
                int orow = r0 + wm + mm * 16 + g * 4 + reg;
                float v = acc[mm][nn][reg];
                if (col < 128) {
                    float kv = v + bk[col];
                    Kall[(size_t)orow * 128 + col] = f2bf(kv > 0.f ? kv : 0.f);
                } else {
                    Pq[(size_t)orow * 128 + (col - 128)] = f2bf(v);
                }
            }
        }
}

// ---------------- qreduce: Q = relu(mean_l Pq + bq)  [4096][128] ----------------
__global__ __launch_bounds__(256) void qreduce(
    const unsigned short* __restrict__ Pq, const float* __restrict__ bq,
    unsigned short* __restrict__ Q)
{
    const int t = blockIdx.x * 256 + threadIdx.x;   // 4096*16
    const int r = t >> 4, jg = t & 15;
    const int b = r >> 11, s = r & 2047;
    float acc[8] = {};
    #pragma unroll
    for (int l = 0; l < 12; ++l) {
        const unsigned short* src = Pq + ((size_t)(l * 2 + b) * Snum + s) * 128 + jg * 8;
        uint4 u = *(const uint4*)src;
        const unsigned short* v = (const unsigned short*)&u;
        #pragma unroll
        for (int i = 0; i < 8; ++i) acc[i] += bf2f(v[i]);
    }
    unsigned short o[8];
    #pragma unroll
    for (int i = 0; i < 8; ++i) {
        float q = acc[i] * (1.0f / 12.0f) + bq[jg * 8 + i];
        o[i] = f2bf(q > 0.f ? q : 0.f);
    }
    *(uint4*)(Q + (size_t)r * 128 + jg * 8) = *(uint4*)o;
}

// ---------------- scores + softmax + weighted hidden sum ----------------
__global__ __launch_bounds__(256) void scores_hbar(
    const float* __restrict__ x,             // [12][2][2048][768] fp32
    const unsigned short* __restrict__ Q,    // [4096][128] bf16, row = b*S+s
    const unsigned short* __restrict__ Kall, // [49152][128] bf16
    unsigned short* __restrict__ hbar)       // [4096][768] bf16
{
    const int wid = threadIdx.x >> 6, lane = threadIdx.x & 63;
    const int r = blockIdx.x * 4 + wid;
    const int b = r >> 11, s = r & 2047;

    const unsigned short* qrow = Q + (size_t)r * 128 + lane * 2;
    const float q0 = bf2f(qrow[0]), q1 = bf2f(qrow[1]);

    float sc[12];
    #pragma unroll
    for (int l = 0; l < 12; ++l) {
        const unsigned short* krow = Kall + ((size_t)(l * 2 + b) * Snum + s) * 128 + lane * 2;
        float p = q0 * bf2f(krow[0]) + q1 * bf2f(krow[1]);
        #pragma unroll
        for (int off = 32; off > 0; off >>= 1) p += __shfl_xor(p, off, 64);
        sc[l] = p * SCALE;
    }
    float m = sc[0];
    #pragma unroll
    for (int l = 1; l < 12; ++l) m = fmaxf(m, sc[l]);
    float att[12], den = 0.f;
    #pragma unroll
    for (int l = 0; l < 12; ++l) { att[l] = __expf(sc[l] - m); den += att[l]; }
    const float inv = 1.0f / den;
    #pragma unroll
    for (int l = 0; l < 12; ++l) att[l] *= inv;

    #pragma unroll
    for (int jv = 0; jv < 3; ++jv) {
        const int d0 = jv * 256 + lane * 4;
        float a0 = 0.f, a1 = 0.f, a2 = 0.f, a3 = 0.f;
        #pragma unroll
        for (int l = 0; l < 12; ++l) {
            const float4 v = *(const float4*)(x + ((size_t)(l * 2 + b) * Snum + s) * 768 + d0);
            a0 += att[l] * v.x; a1 += att[l] * v.y; a2 += att[l] * v.z; a3 += att[l] * v.w;
        }
        ushort4 o;
        o.x = f2bf(a0); o.y = f2bf(a1); o.z = f2bf(a2); o.w = f2bf(a3);
        *(ushort4*)(hbar + (size_t)r * 768 + d0) = o;
    }
}

// ---------------- 64x64 bf16 MFMA GEMM: out = act(A @ Bt^T + bias) ----------------
template <int RELU, int OUT_BF16>
__global__ __launch_bounds__(256) void gemm64(
    const unsigned short* __restrict__ A, const unsigned short* __restrict__ Bt,
    const float* __restrict__ bias, void* __restrict__ out, int M, int N, int K)
{
    __shared__ __align__(16) unsigned short As[64][40];
    __shared__ __align__(16) unsigned short Bs[64][40];
    const int tid = threadIdx.x;
    const int bn = blockIdx.x, bm = blockIdx.y;
    const int wid = tid >> 6, lane = tid & 63;
    const int wm = (wid >> 1) * 32, wn = (wid & 1) * 32;
    const int lr = lane & 15, g = lane >> 4;
    const int r0 = bm * 64, c0 = bn * 64;

    f32x4 acc[2][2] = {};
    const int row = tid >> 2, kc = (tid & 3) * 8;

    for (int k0 = 0; k0 < K; k0 += 32) {
        __syncthreads();
        *(uint4*)&As[row][kc] = *(const uint4*)(A  + (size_t)(r0 + row) * K + k0 + kc);
        *(uint4*)&Bs[row][kc] = *(const uint4*)(Bt + (size_t)(c0 + row) * K + k0 + kc);
        __syncthreads();

        bf16x8 aF[2], bF[2];
        #pragma unroll
        for (int mm = 0; mm < 2; ++mm) aF[mm] = *(const bf16x8*)&As[wm + mm * 16 + lr][g * 8];
        #pragma unroll
        for (int nn = 0; nn < 2; ++nn) bF[nn] = *(const bf16x8*)&Bs[wn + nn * 16 + lr][g * 8];
        #pragma unroll
        for (int mm = 0; mm < 2; ++mm)
            #pragma unroll
            for (int nn = 0; nn < 2; ++nn)
                acc[mm][nn] = __builtin_amdgcn_mfma_f32_16x16x32_bf16(aF[mm], bF[nn], acc[mm][nn], 0, 0, 0);
    }

    #pragma unroll
    for (int mm = 0; mm < 2; ++mm)
        #pragma unroll
        for (int nn = 0; nn < 2; ++nn) {
            int col = c0 + wn + nn * 16 + lr;
            float bcol = bias[col];
            #pragma unroll
            for (int reg = 0; reg < 4; ++reg) {
                int orow = r0 + wm + mm * 16 + g * 4 + reg;
                float v = acc[mm][nn][reg] + bcol;
                if (RELU) v = v > 0.f ? v : 0.f;
                if (OUT_BF16) ((unsigned short*)out)[(size_t)orow * N + col] = f2bf(v);
                else          ((float*)out)[(size_t)orow * N + col] = v;
            }
        }
}

// ---------------- final GEMM: out = mid @ W2t^T + b2, fp32 out, XCD-swizzled ----------------
// M=4096, N=32000, K=256. Grid: 8000 blocks 1D. bn-major chunking per XCD for W2t L2 locality.
__global__ __launch_bounds__(256) void gemm_out(
    const unsigned short* __restrict__ A,   // [4096][256] bf16
    const unsigned short* __restrict__ Bt,  // [32000][256] bf16
    const float* __restrict__ bias, float* __restrict__ out)
{
    __shared__ __align__(16) unsigned short As[128 * 32];
    __shared__ __align__(16) unsigned short Bs[128 * 32];
    const int K = 256, N = 32000;
    const int orig = blockIdx.x;                 // 8000
    const int swz = (orig & 7) * 1000 + (orig >> 3);
    const int bn = swz >> 5;                     // [0,250)
    const int bm = swz & 31;                     // [0,32)
    const int tid = threadIdx.x;
    const int wid = tid >> 6, lane = tid & 63;
    const int wm = (wid >> 1) * 64, wn = (wid & 1) * 64;
    const int lr = lane & 15, g = lane >> 4;
    const int r0 = bm * 128, c0 = bn * 128;

    f32x4 acc[4][4] = {};

    for (int k0 = 0; k0 < K; k0 += 32) {
        __syncthreads();
        #pragma unroll
        for (int c = 0; c < 2; ++c) {
            int rr = wid * 32 + c * 16;
            gld_lds16(A  + (size_t)(r0 + rr + (lane >> 2)) * K + k0 + (lane & 3) * 8, &As[rr * 32]);
            gld_lds16(Bt + (size_t)(c0 + rr + (lane >> 2)) * K + k0 + (lane & 3) * 8, &Bs[rr * 32]);
        }
        __syncthreads();

        bf16x8 aF[4], bF[4];
        #pragma unroll
        for (int mm = 0; mm < 4; ++mm) aF[mm] = *(const bf16x8*)&As[(wm + mm * 16 + lr) * 32 + g * 8];
        #pragma unroll
        for (int nn = 0; nn < 4; ++nn) bF[nn] = *(const bf16x8*)&Bs[(wn + nn * 16 + lr) * 32 + g * 8];
        #pragma unroll
        for (int mm = 0; mm < 4; ++mm)
            #pragma unroll
            for (int nn = 0; nn < 4; ++nn)
                acc[mm][nn] = __builtin_amdgcn_mfma_f32_16x16x32_bf16(aF[mm], bF[nn], acc[mm][nn], 0, 0, 0);
    }

    #pragma unroll
    for (int mm = 0; mm < 4; ++mm)
        #pragma unroll
        for (int nn = 0; nn < 4; ++nn) {
            int col = c0 + wn + nn * 16 + lr;
            float bcol = bias[col];
            #pragma unroll
            for (int reg = 0; reg < 4; ++reg) {
                int orow = r0 + wm + mm * 16 + g * 4 + reg;
                out[(size_t)orow * N + col] = acc[mm][nn][reg] + bcol;
            }
        }
}

extern "C" void kernel_launch(void* const* d_in, const int* in_sizes, int n_in,
                              void* d_out, int out_size, void* d_ws, size_t ws_size,
                              hipStream_t stream) {
    (void)in_sizes; (void)n_in; (void)out_size; (void)ws_size;

    const float* x  = (const float*)d_in[0];
    const float* Wq = (const float*)d_in[1];
    const float* bq = (const float*)d_in[2];
    const float* Wk = (const float*)d_in[3];
    const float* bk = (const float*)d_in[4];
    const float* Wv = (const float*)d_in[5];
    const float* bv = (const float*)d_in[6];
    const float* W1 = (const float*)d_in[7];
    const float* b1 = (const float*)d_in[8];
    const float* W2 = (const float*)d_in[9];
    const float* b2 = (const float*)d_in[10];

    char* p = (char*)d_ws;
    unsigned short* Wqkt  = (unsigned short*)p; p += (size_t)256 * 768 * 2;   // [Wk^T | Wq^T]
    unsigned short* Wvt   = (unsigned short*)p; p += (size_t)512 * 768 * 2;
    unsigned short* W1t   = (unsigned short*)p; p += (size_t)256 * 512 * 2;
    unsigned short* W2t   = (unsigned short*)p; p += (size_t)32000 * 256 * 2;
    unsigned short* Qb    = (unsigned short*)p; p += (size_t)4096 * 128 * 2;
    unsigned short* Kall  = (unsigned short*)p; p += (size_t)49152 * 128 * 2;
    unsigned short* Pq    = (unsigned short*)p; p += (size_t)49152 * 128 * 2;
    unsigned short* hbar  = (unsigned short*)p; p += (size_t)4096 * 768 * 2;
    unsigned short* aggb  = (unsigned short*)p; p += (size_t)4096 * 512 * 2;
    unsigned short* midb  = (unsigned short*)p; p += (size_t)4096 * 256 * 2;

    // weight transpose+convert
    transpose_f2bf<<<dim3(128 / 32, 768 / 32), dim3(256), 0, stream>>>(Wk, Wqkt, 768, 128);
    transpose_f2bf<<<dim3(128 / 32, 768 / 32), dim3(256), 0, stream>>>(Wq, Wqkt + (size_t)128 * 768, 768, 128);
    transpose_f2bf<<<dim3(512 / 32, 768 / 32), dim3(256), 0, stream>>>(Wv, Wvt, 768, 512);
    transpose_f2bf<<<dim3(256 / 32, 512 / 32), dim3(256), 0, stream>>>(W1, W1t, 512, 256);
    transpose_f2bf<<<dim3(32000 / 32, 256 / 32), dim3(256), 0, stream>>>(W2, W2t, 256, 32000);

    // one pass over x: Kall = relu(x@Wk+bk), Pq = x@Wq
    proj_qk<<<dim3(49152 / 128), dim3(512), 0, stream>>>(x, Wqkt, bk, Kall, Pq);

    // Q = relu(mean_l Pq + bq)
    qreduce<<<dim3(4096 * 16 / 256), dim3(256), 0, stream>>>(Pq, bq, Qb);

    // scores -> softmax -> hbar
    scores_hbar<<<dim3(1024), dim3(256), 0, stream>>>(x, Qb, Kall, hbar);

    // agg = hbar @ Wv + bv
    gemm64<0, 1><<<dim3(512 / 64, 4096 / 64), dim3(256), 0, stream>>>(
        hbar, Wvt, bv, aggb, 4096, 512, 768);

    // mid = relu(agg @ W1 + b1)
    gemm64<1, 1><<<dim3(256 / 64, 4096 / 64), dim3(256), 0, stream>>>(
        aggb, W1t, b1, midb, 4096, 256, 512);

    // out = mid @ W2 + b2  (fp32)
    gemm_out<<<dim3(8000), dim3(256), 0, stream>>>(midb, W2t, b2, (float*)d_out);
}

// Round 4
// 340.167 us; speedup vs baseline: 2.0180x; 1.0018x over previous
//
#include <hip/hip_runtime.h>

#define Snum 2048
#define SCALE 0.08838834764831845f

typedef __attribute__((ext_vector_type(8))) __bf16 bf16x8;
typedef __attribute__((ext_vector_type(4))) float f32x4;

__device__ inline unsigned short f2bf(float f) {
    unsigned int u = __float_as_uint(f);
    unsigned int r = u + 0x7FFFu + ((u >> 16) & 1u);
    return (unsigned short)(r >> 16);
}
__device__ inline float bf2f(unsigned short u) {
    return __uint_as_float(((unsigned)u) << 16);
}
__device__ inline void gld_lds16(const unsigned short* g, unsigned short* l) {
    __builtin_amdgcn_global_load_lds(
        (const __attribute__((address_space(1))) unsigned int*)g,
        (__attribute__((address_space(3))) unsigned int*)l, 16, 0, 0);
}

// ---------------- tiled transpose + fp32->bf16: in [K][N] -> out [N][K] ----------------
__global__ __launch_bounds__(256) void transpose_f2bf(
    const float* __restrict__ in, unsigned short* __restrict__ out, int K, int N)
{
    __shared__ float t[32][33];
    const int bx = blockIdx.x;           // N / 32
    const int by = blockIdx.y;           // K / 32
    const int tx = threadIdx.x & 31, ty = threadIdx.x >> 5;
    #pragma unroll
    for (int i = 0; i < 4; ++i) {
        int k = by * 32 + ty + i * 8, n = bx * 32 + tx;
        t[ty + i * 8][tx] = in[(size_t)k * N + n];
    }
    __syncthreads();
    #pragma unroll
    for (int i = 0; i < 4; ++i) {
        int n = bx * 32 + ty + i * 8, k = by * 32 + tx;
        out[(size_t)n * K + k] = f2bf(t[tx][ty + i * 8]);
    }
}

// ---------------- proj_qk: one pass over x -> Kall = relu(x@Wk+bk), Pq = x@Wq ----------------
// Tile 64x256, 256 threads (4 waves, each 64x64), 2-phase double-buffered.
// A: x fp32 [49152][768]; Bt: Wqkt bf16 [256][768] (rows 0-127 Wk^T, 128-255 Wq^T)
__global__ __launch_bounds__(256) void proj_qk(
    const float* __restrict__ x, const unsigned short* __restrict__ Bt,
    const float* __restrict__ bk,
    unsigned short* __restrict__ Kall,   // [49152][128] bf16
    unsigned short* __restrict__ Pq)     // [49152][128] bf16
{
    __shared__ __align__(16) unsigned short As[2][64 * 32];    // 2 x 4 KB
    __shared__ __align__(16) unsigned short Bs[2][256 * 32];   // 2 x 16 KB
    const int tid = threadIdx.x;
    const int wid = tid >> 6, lane = tid & 63;
    const int wn = wid * 64;
    const int lr = lane & 15, g = lane >> 4;
    const int r0 = blockIdx.x * 64;
    const int K = 768, NT = K / 32;

    const int arow = tid >> 2, akc = (tid & 3) * 8;   // A: 64 rows x 32 k, 8 floats/thread

    f32x4 acc[4][4] = {};

    // prologue: tile 0
    float4 a0 = *(const float4*)(x + (size_t)(r0 + arow) * K + akc);
    float4 a1 = *(const float4*)(x + (size_t)(r0 + arow) * K + akc + 4);
    {
        unsigned short v[8];
        v[0] = f2bf(a0.x); v[1] = f2bf(a0.y); v[2] = f2bf(a0.z); v[3] = f2bf(a0.w);
        v[4] = f2bf(a1.x); v[5] = f2bf(a1.y); v[6] = f2bf(a1.z); v[7] = f2bf(a1.w);
        *(uint4*)&As[0][arow * 32 + akc] = *(uint4*)v;
    }
    #pragma unroll
    for (int c = 0; c < 4; ++c) {
        int rr = wid * 64 + c * 16;
        gld_lds16(Bt + (size_t)(rr + (lane >> 2)) * K + (lane & 3) * 8, &Bs[0][rr * 32]);
    }
    __syncthreads();

    for (int t = 0; t < NT; ++t) {
        const int cur = t & 1, nxt = cur ^ 1;
        // issue next-tile loads before consuming current
        if (t + 1 < NT) {
            const int k0 = (t + 1) * 32;
            a0 = *(const float4*)(x + (size_t)(r0 + arow) * K + k0 + akc);
            a1 = *(const float4*)(x + (size_t)(r0 + arow) * K + k0 + akc + 4);
            #pragma unroll
            for (int c = 0; c < 4; ++c) {
                int rr = wid * 64 + c * 16;
                gld_lds16(Bt + (size_t)(rr + (lane >> 2)) * K + k0 + (lane & 3) * 8,
                          &Bs[nxt][rr * 32]);
            }
        }

        // compute on current buffer
        bf16x8 aF[4], bF[4];
        #pragma unroll
        for (int mm = 0; mm < 4; ++mm) aF[mm] = *(const bf16x8*)&As[cur][(mm * 16 + lr) * 32 + g * 8];
        #pragma unroll
        for (int nn = 0; nn < 4; ++nn) bF[nn] = *(const bf16x8*)&Bs[cur][(wn + nn * 16 + lr) * 32 + g * 8];
        #pragma unroll
        for (int mm = 0; mm < 4; ++mm)
            #pragma unroll
            for (int nn = 0; nn < 4; ++nn)
                acc[mm][nn] = __builtin_amdgcn_mfma_f32_16x16x32_bf16(aF[mm], bF[nn], acc[mm][nn], 0, 0, 0);

        // convert+write A for next tile (waits on a0/a1 loads only)
        if (t + 1 < NT) {
            unsigned short v[8];
            v[0] = f2bf(a0.x); v[1] = f2bf(a0.y); v[2] = f2bf(a0.z); v[3] = f2bf(a0.w);
            v[4] = f2bf(a1.x); v[5] = f2bf(a1.y); v[6] = f2bf(a1.z); v[7] = f2bf(a1.w);
            *(uint4*)&As[nxt][arow * 32 + akc] = *(uint4*)v;
        }
        __syncthreads();
    }

    #pragma unroll
    for (int mm = 0; mm < 4; ++mm)
        #pragma unroll
        for (int nn = 0; nn < 4; ++nn) {
            int col = wn + nn * 16 + lr;
            #pragma unroll
            for (int reg = 0; reg < 4; ++reg) {
                int orow = r0 + mm * 16 + g * 4 + reg;
                float v = acc[mm][nn][reg];
                if (col < 128) {
                    float kv = v + bk[col];
                    Kall[(size_t)orow * 128 + col] = f2bf(kv > 0.f ? kv : 0.f);
                } else {
                    Pq[(size_t)orow * 128 + (col - 128)] = f2bf(v);
                }
            }
        }
}

// ---------------- scores + softmax + weighted hidden sum (q fused in) ----------------
__global__ __launch_bounds__(256) void scores_hbar(
    const float* __restrict__ x,             // [12][2][2048][768] fp32
    const unsigned short* __restrict__ Pq,   // [49152][128] bf16
    const float* __restrict__ bq,            // [128]
    const unsigned short* __restrict__ Kall, // [49152][128] bf16
    unsigned short* __restrict__ hbar)       // [4096][768] bf16
{
    const int wid = threadIdx.x >> 6, lane = threadIdx.x & 63;
    const int r = blockIdx.x * 4 + wid;
    const int b = r >> 11, s = r & 2047;

    // q = relu(mean_l Pq + bq) for this lane's two columns
    float qa = 0.f, qb_ = 0.f;
    #pragma unroll
    for (int l = 0; l < 12; ++l) {
        const unsigned short* prow = Pq + ((size_t)(l * 2 + b) * Snum + s) * 128 + lane * 2;
        unsigned int u = *(const unsigned int*)prow;
        qa += bf2f((unsigned short)(u & 0xFFFF));
        qb_ += bf2f((unsigned short)(u >> 16));
    }
    float q0 = qa * (1.0f / 12.0f) + bq[lane * 2];
    float q1 = qb_ * (1.0f / 12.0f) + bq[lane * 2 + 1];
    q0 = q0 > 0.f ? q0 : 0.f;
    q1 = q1 > 0.f ? q1 : 0.f;
    // match bf16 storage rounding of previous path
    q0 = bf2f(f2bf(q0)); q1 = bf2f(f2bf(q1));

    float sc[12];
    #pragma unroll
    for (int l = 0; l < 12; ++l) {
        const unsigned short* krow = Kall + ((size_t)(l * 2 + b) * Snum + s) * 128 + lane * 2;
        unsigned int u = *(const unsigned int*)krow;
        float p = q0 * bf2f((unsigned short)(u & 0xFFFF)) + q1 * bf2f((unsigned short)(u >> 16));
        #pragma unroll
        for (int off = 32; off > 0; off >>= 1) p += __shfl_xor(p, off, 64);
        sc[l] = p * SCALE;
    }
    float m = sc[0];
    #pragma unroll
    for (int l = 1; l < 12; ++l) m = fmaxf(m, sc[l]);
    float att[12], den = 0.f;
    #pragma unroll
    for (int l = 0; l < 12; ++l) { att[l] = __expf(sc[l] - m); den += att[l]; }
    const float inv = 1.0f / den;
    #pragma unroll
    for (int l = 0; l < 12; ++l) att[l] *= inv;

    #pragma unroll
    for (int jv = 0; jv < 3; ++jv) {
        const int d0 = jv * 256 + lane * 4;
        float a0 = 0.f, a1 = 0.f, a2 = 0.f, a3 = 0.f;
        #pragma unroll
        for (int l = 0; l < 12; ++l) {
            const float4 v = *(const float4*)(x + ((size_t)(l * 2 + b) * Snum + s) * 768 + d0);
            a0 += att[l] * v.x; a1 += att[l] * v.y; a2 += att[l] * v.z; a3 += att[l] * v.w;
        }
        ushort4 o;
        o.x = f2bf(a0); o.y = f2bf(a1); o.z = f2bf(a2); o.w = f2bf(a3);
        *(ushort4*)(hbar + (size_t)r * 768 + d0) = o;
    }
}

// ---------------- 64x64 bf16 MFMA GEMM: out = act(A @ Bt^T + bias) ----------------
template <int RELU, int OUT_BF16>
__global__ __launch_bounds__(256) void gemm64(
    const unsigned short* __restrict__ A, const unsigned short* __restrict__ Bt,
    const float* __restrict__ bias, void* __restrict__ out, int M, int N, int K)
{
    __shared__ __align__(16) unsigned short As[64][40];
    __shared__ __align__(16) unsigned short Bs[64][40];
    const int tid = threadIdx.x;
    const int bn = blockIdx.x, bm = blockIdx.y;
    const int wid = tid >> 6, lane = tid & 63;
    const int wm = (wid >> 1) * 32, wn = (wid & 1) * 32;
    const int lr = lane & 15, g = lane >> 4;
    const int r0 = bm * 64, c0 = bn * 64;

    f32x4 acc[2][2] = {};
    const int row = tid >> 2, kc = (tid & 3) * 8;

    for (int k0 = 0; k0 < K; k0 += 32) {
        __syncthreads();
        *(uint4*)&As[row][kc] = *(const uint4*)(A  + (size_t)(r0 + row) * K + k0 + kc);
        *(uint4*)&Bs[row][kc] = *(const uint4*)(Bt + (size_t)(c0 + row) * K + k0 + kc);
        __syncthreads();

        bf16x8 aF[2], bF[2];
        #pragma unroll
        for (int mm = 0; mm < 2; ++mm) aF[mm] = *(const bf16x8*)&As[wm + mm * 16 + lr][g * 8];
        #pragma unroll
        for (int nn = 0; nn < 2; ++nn) bF[nn] = *(const bf16x8*)&Bs[wn + nn * 16 + lr][g * 8];
        #pragma unroll
        for (int mm = 0; mm < 2; ++mm)
            #pragma unroll
            for (int nn = 0; nn < 2; ++nn)
                acc[mm][nn] = __builtin_amdgcn_mfma_f32_16x16x32_bf16(aF[mm], bF[nn], acc[mm][nn], 0, 0, 0);
    }

    #pragma unroll
    for (int mm = 0; mm < 2; ++mm)
        #pragma unroll
        for (int nn = 0; nn < 2; ++nn) {
            int col = c0 + wn + nn * 16 + lr;
            float bcol = bias[col];
            #pragma unroll
            for (int reg = 0; reg < 4; ++reg) {
                int orow = r0 + wm + mm * 16 + g * 4 + reg;
                float v = acc[mm][nn][reg] + bcol;
                if (RELU) v = v > 0.f ? v : 0.f;
                if (OUT_BF16) ((unsigned short*)out)[(size_t)orow * N + col] = f2bf(v);
                else          ((float*)out)[(size_t)orow * N + col] = v;
            }
        }
}

// ---------------- final GEMM: out = mid @ W2t^T + b2, fp32, XCD-swizzled, 2-phase dbuf ----------------
// M=4096, N=32000, K=256. Grid 8000 blocks.
__global__ __launch_bounds__(256) void gemm_out(
    const unsigned short* __restrict__ A,   // [4096][256] bf16
    const unsigned short* __restrict__ Bt,  // [32000][256] bf16
    const float* __restrict__ bias, float* __restrict__ out)
{
    __shared__ __align__(16) unsigned short As[2][128 * 32];
    __shared__ __align__(16) unsigned short Bs[2][128 * 32];
    const int K = 256, N = 32000, NT = K / 32;
    const int orig = blockIdx.x;                 // 8000
    const int swz = (orig & 7) * 1000 + (orig >> 3);
    const int bn = swz >> 5;                     // [0,250)
    const int bm = swz & 31;                     // [0,32)
    const int tid = threadIdx.x;
    const int wid = tid >> 6, lane = tid & 63;
    const int wm = (wid >> 1) * 64, wn = (wid & 1) * 64;
    const int lr = lane & 15, g = lane >> 4;
    const int r0 = bm * 128, c0 = bn * 128;

    f32x4 acc[4][4] = {};

    // prologue: stage tile 0
    #pragma unroll
    for (int c = 0; c < 2; ++c) {
        int rr = wid * 32 + c * 16;
        gld_lds16(A  + (size_t)(r0 + rr + (lane >> 2)) * K + (lane & 3) * 8, &As[0][rr * 32]);
        gld_lds16(Bt + (size_t)(c0 + rr + (lane >> 2)) * K + (lane & 3) * 8, &Bs[0][rr * 32]);
    }
    __syncthreads();

    for (int t = 0; t < NT; ++t) {
        const int cur = t & 1, nxt = cur ^ 1;
        if (t + 1 < NT) {
            const int k0 = (t + 1) * 32;
            #pragma unroll
            for (int c = 0; c < 2; ++c) {
                int rr = wid * 32 + c * 16;
                gld_lds16(A  + (size_t)(r0 + rr + (lane >> 2)) * K + k0 + (lane & 3) * 8, &As[nxt][rr * 32]);
                gld_lds16(Bt + (size_t)(c0 + rr + (lane >> 2)) * K + k0 + (lane & 3) * 8, &Bs[nxt][rr * 32]);
            }
        }

        bf16x8 aF[4], bF[4];
        #pragma unroll
        for (int mm = 0; mm < 4; ++mm) aF[mm] = *(const bf16x8*)&As[cur][(wm + mm * 16 + lr) * 32 + g * 8];
        #pragma unroll
        for (int nn = 0; nn < 4; ++nn) bF[nn] = *(const bf16x8*)&Bs[cur][(wn + nn * 16 + lr) * 32 + g * 8];
        #pragma unroll
        for (int mm = 0; mm < 4; ++mm)
            #pragma unroll
            for (int nn = 0; nn < 4; ++nn)
                acc[mm][nn] = __builtin_amdgcn_mfma_f32_16x16x32_bf16(aF[mm], bF[nn], acc[mm][nn], 0, 0, 0);
        __syncthreads();
    }

    #pragma unroll
    for (int mm = 0; mm < 4; ++mm)
        #pragma unroll
        for (int nn = 0; nn < 4; ++nn) {
            int col = c0 + wn + nn * 16 + lr;
            float bcol = bias[col];
            #pragma unroll
            for (int reg = 0; reg < 4; ++reg) {
                int orow = r0 + wm + mm * 16 + g * 4 + reg;
                out[(size_t)orow * N + col] = acc[mm][nn][reg] + bcol;
            }
        }
}

extern "C" void kernel_launch(void* const* d_in, const int* in_sizes, int n_in,
                              void* d_out, int out_size, void* d_ws, size_t ws_size,
                              hipStream_t stream) {
    (void)in_sizes; (void)n_in; (void)out_size; (void)ws_size;

    const float* x  = (const float*)d_in[0];
    const float* Wq = (const float*)d_in[1];
    const float* bq = (const float*)d_in[2];
    const float* Wk = (const float*)d_in[3];
    const float* bk = (const float*)d_in[4];
    const float* Wv = (const float*)d_in[5];
    const float* bv = (const float*)d_in[6];
    const float* W1 = (const float*)d_in[7];
    const float* b1 = (const float*)d_in[8];
    const float* W2 = (const float*)d_in[9];
    const float* b2 = (const float*)d_in[10];

    char* p = (char*)d_ws;
    unsigned short* Wqkt  = (unsigned short*)p; p += (size_t)256 * 768 * 2;   // [Wk^T | Wq^T]
    unsigned short* Wvt   = (unsigned short*)p; p += (size_t)512 * 768 * 2;
    unsigned short* W1t   = (unsigned short*)p; p += (size_t)256 * 512 * 2;
    unsigned short* W2t   = (unsigned short*)p; p += (size_t)32000 * 256 * 2;
    unsigned short* Kall  = (unsigned short*)p; p += (size_t)49152 * 128 * 2;
    unsigned short* Pq    = (unsigned short*)p; p += (size_t)49152 * 128 * 2;
    unsigned short* hbar  = (unsigned short*)p; p += (size_t)4096 * 768 * 2;
    unsigned short* aggb  = (unsigned short*)p; p += (size_t)4096 * 512 * 2;
    unsigned short* midb  = (unsigned short*)p; p += (size_t)4096 * 256 * 2;

    // weight transpose+convert
    transpose_f2bf<<<dim3(128 / 32, 768 / 32), dim3(256), 0, stream>>>(Wk, Wqkt, 768, 128);
    transpose_f2bf<<<dim3(128 / 32, 768 / 32), dim3(256), 0, stream>>>(Wq, Wqkt + (size_t)128 * 768, 768, 128);
    transpose_f2bf<<<dim3(512 / 32, 768 / 32), dim3(256), 0, stream>>>(Wv, Wvt, 768, 512);
    transpose_f2bf<<<dim3(256 / 32, 512 / 32), dim3(256), 0, stream>>>(W1, W1t, 512, 256);
    transpose_f2bf<<<dim3(32000 / 32, 256 / 32), dim3(256), 0, stream>>>(W2, W2t, 256, 32000);

    // one pass over x: Kall = relu(x@Wk+bk), Pq = x@Wq
    proj_qk<<<dim3(49152 / 64), dim3(256), 0, stream>>>(x, Wqkt, bk, Kall, Pq);

    // scores (q fused) -> softmax -> hbar
    scores_hbar<<<dim3(1024), dim3(256), 0, stream>>>(x, Pq, bq, Kall, hbar);

    // agg = hbar @ Wv + bv
    gemm64<0, 1><<<dim3(512 / 64, 4096 / 64), dim3(256), 0, stream>>>(
        hbar, Wvt, bv, aggb, 4096, 512, 768);

    // mid = relu(agg @ W1 + b1)
    gemm64<1, 1><<<dim3(256 / 64, 4096 / 64), dim3(256), 0, stream>>>(
        aggb, W1t, b1, midb, 4096, 256, 512);

    // out = mid @ W2 + b2  (fp32)
    gemm_out<<<dim3(8000), dim3(256), 0, stream>>>(midb, W2t, b2, (float*)d_out);
}